// Round 1
// baseline (128.972 us; speedup 1.0000x reference)
//
#include <hip/hip_runtime.h>

namespace {

constexpr int kB = 8;
constexpr int kV = 5023;
constexpr int kF = 9976;
constexpr int kH = 512;
constexpr int kW = 512;
constexpr int kL = 5;
constexpr int kHW = kH * kW;

__device__ __forceinline__ void cross3(float ax, float ay, float az,
                                       float bx, float by, float bz,
                                       float& cx, float& cy, float& cz) {
  cx = ay * bz - az * by;
  cy = az * bx - ax * bz;
  cz = ax * by - ay * bx;
}

// One thread per (batch, face): accumulate the three reference cross products
// into per-vertex normal accumulators for both meshes.
__global__ void face_scatter_kernel(const float* __restrict__ verts,
                                    const float* __restrict__ tverts,
                                    const int* __restrict__ faces,
                                    float* __restrict__ acc_n,
                                    float* __restrict__ acc_t) {
  int idx = blockIdx.x * blockDim.x + threadIdx.x;
  if (idx >= kB * kF) return;
  int b = idx / kF;
  int f = idx - b * kF;
  int i0 = faces[f * 3 + 0];
  int i1 = faces[f * 3 + 1];
  int i2 = faces[f * 3 + 2];

  // mesh 1: vertices
  {
    const float* vb = verts + (size_t)b * kV * 3;
    float v0x = vb[i0 * 3 + 0], v0y = vb[i0 * 3 + 1], v0z = vb[i0 * 3 + 2];
    float v1x = vb[i1 * 3 + 0], v1y = vb[i1 * 3 + 1], v1z = vb[i1 * 3 + 2];
    float v2x = vb[i2 * 3 + 0], v2y = vb[i2 * 3 + 1], v2z = vb[i2 * 3 + 2];
    float* ab = acc_n + (size_t)b * kV * 3;
    float cx, cy, cz;
    // n[faces[:,1]] += cross(v2-v1, v0-v1)
    cross3(v2x - v1x, v2y - v1y, v2z - v1z, v0x - v1x, v0y - v1y, v0z - v1z, cx, cy, cz);
    atomicAdd(&ab[i1 * 3 + 0], cx);
    atomicAdd(&ab[i1 * 3 + 1], cy);
    atomicAdd(&ab[i1 * 3 + 2], cz);
    // n[faces[:,2]] += cross(v0-v2, v1-v2)
    cross3(v0x - v2x, v0y - v2y, v0z - v2z, v1x - v2x, v1y - v2y, v1z - v2z, cx, cy, cz);
    atomicAdd(&ab[i2 * 3 + 0], cx);
    atomicAdd(&ab[i2 * 3 + 1], cy);
    atomicAdd(&ab[i2 * 3 + 2], cz);
    // n[faces[:,0]] += cross(v1-v0, v2-v0)
    cross3(v1x - v0x, v1y - v0y, v1z - v0z, v2x - v0x, v2y - v0y, v2z - v0z, cx, cy, cz);
    atomicAdd(&ab[i0 * 3 + 0], cx);
    atomicAdd(&ab[i0 * 3 + 1], cy);
    atomicAdd(&ab[i0 * 3 + 2], cz);
  }

  // mesh 2: transformed vertices with z += 10 (kept fp-faithful to reference)
  {
    const float* vb = tverts + (size_t)b * kV * 3;
    float v0x = vb[i0 * 3 + 0], v0y = vb[i0 * 3 + 1], v0z = vb[i0 * 3 + 2] + 10.0f;
    float v1x = vb[i1 * 3 + 0], v1y = vb[i1 * 3 + 1], v1z = vb[i1 * 3 + 2] + 10.0f;
    float v2x = vb[i2 * 3 + 0], v2y = vb[i2 * 3 + 1], v2z = vb[i2 * 3 + 2] + 10.0f;
    float* ab = acc_t + (size_t)b * kV * 3;
    float cx, cy, cz;
    cross3(v2x - v1x, v2y - v1y, v2z - v1z, v0x - v1x, v0y - v1y, v0z - v1z, cx, cy, cz);
    atomicAdd(&ab[i1 * 3 + 0], cx);
    atomicAdd(&ab[i1 * 3 + 1], cy);
    atomicAdd(&ab[i1 * 3 + 2], cz);
    cross3(v0x - v2x, v0y - v2y, v0z - v2z, v1x - v2x, v1y - v2y, v1z - v2z, cx, cy, cz);
    atomicAdd(&ab[i2 * 3 + 0], cx);
    atomicAdd(&ab[i2 * 3 + 1], cy);
    atomicAdd(&ab[i2 * 3 + 2], cz);
    cross3(v1x - v0x, v1y - v0y, v1z - v0z, v2x - v0x, v2y - v0y, v2z - v0z, cx, cy, cz);
    atomicAdd(&ab[i0 * 3 + 0], cx);
    atomicAdd(&ab[i0 * 3 + 1], cy);
    atomicAdd(&ab[i0 * 3 + 2], cz);
  }
}

// Normalize vertex normals in place; produce tnorm z; pre-normalize lights.
__global__ void normalize_kernel(float* __restrict__ acc_n,
                                 const float* __restrict__ acc_t,
                                 float* __restrict__ tz,
                                 const float* __restrict__ lights,
                                 float* __restrict__ ldir) {
  int idx = blockIdx.x * blockDim.x + threadIdx.x;
  if (idx < kB * kV) {
    float x = acc_n[idx * 3 + 0];
    float y = acc_n[idx * 3 + 1];
    float z = acc_n[idx * 3 + 2];
    float inv = 1.0f / fmaxf(sqrtf(x * x + y * y + z * z), 1e-6f);
    acc_n[idx * 3 + 0] = x * inv;
    acc_n[idx * 3 + 1] = y * inv;
    acc_n[idx * 3 + 2] = z * inv;

    float tx = acc_t[idx * 3 + 0];
    float ty = acc_t[idx * 3 + 1];
    float tzv = acc_t[idx * 3 + 2];
    float invt = 1.0f / fmaxf(sqrtf(tx * tx + ty * ty + tzv * tzv), 1e-6f);
    tz[idx] = tzv * invt;
  }
  if (idx < kB * kL) {
    float dx = lights[idx * 6 + 0];
    float dy = lights[idx * 6 + 1];
    float dz = lights[idx * 6 + 2];
    float inv = 1.0f / fmaxf(sqrtf(dx * dx + dy * dy + dz * dz), 1e-12f);
    ldir[idx * 6 + 0] = dx * inv;
    ldir[idx * 6 + 1] = dy * inv;
    ldir[idx * 6 + 2] = dz * inv;
    ldir[idx * 6 + 3] = lights[idx * 6 + 3];
    ldir[idx * 6 + 4] = lights[idx * 6 + 4];
    ldir[idx * 6 + 5] = lights[idx * 6 + 5];
  }
}

// One thread per pixel.
__global__ void pixel_kernel(const int* __restrict__ p2f,
                             const float* __restrict__ bary,
                             const int* __restrict__ faces,
                             const float* __restrict__ normals,
                             const float* __restrict__ tz,
                             const float* __restrict__ ldir,
                             const float* __restrict__ images,
                             float* __restrict__ out) {
  int pid = blockIdx.x * blockDim.x + threadIdx.x;
  if (pid >= kB * kHW) return;
  int b = pid / kHW;
  int p = pid - b * kHW;

  int f = p2f[pid];
  bool valid = f < kF;
  f = valid ? f : (kF - 1);

  int i0 = faces[f * 3 + 0];
  int i1 = faces[f * 3 + 1];
  int i2 = faces[f * 3 + 2];

  float b0 = bary[(size_t)pid * 3 + 0];
  float b1 = bary[(size_t)pid * 3 + 1];
  float b2 = bary[(size_t)pid * 3 + 2];
  float s = b0 + b1 + b2;
  b0 /= s;
  b1 /= s;
  b2 /= s;

  const float* tzb = tz + (size_t)b * kV;
  float tzi = b0 * tzb[i0] + b1 * tzb[i1] + b2 * tzb[i2];
  bool alpha = valid && (tzi < 0.15f);

  size_t ib = (size_t)b * 3 * kHW + p;
  float o0, o1, o2;
  if (alpha) {
    const float* nb = normals + (size_t)b * kV * 3;
    float nx = b0 * nb[i0 * 3 + 0] + b1 * nb[i1 * 3 + 0] + b2 * nb[i2 * 3 + 0];
    float ny = b0 * nb[i0 * 3 + 1] + b1 * nb[i1 * 3 + 1] + b2 * nb[i2 * 3 + 1];
    float nz = b0 * nb[i0 * 3 + 2] + b1 * nb[i1 * 3 + 2] + b2 * nb[i2 * 3 + 2];
    const float* lb = ldir + (size_t)b * kL * 6;
    float s0 = 0.f, s1 = 0.f, s2 = 0.f;
#pragma unroll
    for (int l = 0; l < kL; ++l) {
      float d = nx * lb[l * 6 + 0] + ny * lb[l * 6 + 1] + nz * lb[l * 6 + 2];
      d = fminf(fmaxf(d, 0.0f), 1.0f);
      s0 += d * lb[l * 6 + 3];
      s1 += d * lb[l * 6 + 4];
      s2 += d * lb[l * 6 + 5];
    }
    const float k = (180.0f / 255.0f) / (float)kL;
    o0 = k * s0;
    o1 = k * s1;
    o2 = k * s2;
  } else {
    o0 = images[ib + 0 * (size_t)kHW];
    o1 = images[ib + 1 * (size_t)kHW];
    o2 = images[ib + 2 * (size_t)kHW];
  }
  out[ib + 0 * (size_t)kHW] = o0;
  out[ib + 1 * (size_t)kHW] = o1;
  out[ib + 2 * (size_t)kHW] = o2;
}

}  // namespace

extern "C" void kernel_launch(void* const* d_in, const int* in_sizes, int n_in,
                              void* d_out, int out_size, void* d_ws, size_t ws_size,
                              hipStream_t stream) {
  const float* vertices = (const float*)d_in[0];
  const float* tvertices = (const float*)d_in[1];
  const float* lights = (const float*)d_in[2];
  const float* images = (const float*)d_in[3];
  const float* bary = (const float*)d_in[4];
  const int* faces = (const int*)d_in[5];
  const int* p2f = (const int*)d_in[6];
  float* out = (float*)d_out;

  float* ws = (float*)d_ws;
  float* acc_n = ws;                               // B*V*3
  float* acc_t = acc_n + (size_t)kB * kV * 3;      // B*V*3
  float* tz = acc_t + (size_t)kB * kV * 3;         // B*V
  float* ldir = tz + (size_t)kB * kV;              // B*L*6

  hipMemsetAsync(acc_n, 0, (size_t)2 * kB * kV * 3 * sizeof(float), stream);

  {
    int n = kB * kF;
    face_scatter_kernel<<<(n + 255) / 256, 256, 0, stream>>>(vertices, tvertices, faces,
                                                             acc_n, acc_t);
  }
  {
    int n = kB * kV;
    normalize_kernel<<<(n + 255) / 256, 256, 0, stream>>>(acc_n, acc_t, tz, lights, ldir);
  }
  {
    int n = kB * kHW;
    pixel_kernel<<<(n + 255) / 256, 256, 0, stream>>>(p2f, bary, faces, acc_n, tz, ldir,
                                                      images, out);
  }
}

// Round 2
// 73.775 us; speedup vs baseline: 1.7482x; 1.7482x over previous
//
#include <hip/hip_runtime.h>

namespace {

constexpr int kB = 8;
constexpr int kV = 5023;
constexpr int kF = 9976;
constexpr int kH = 512;
constexpr int kW = 512;
constexpr int kL = 5;
constexpr int kHW = kH * kW;
constexpr int kCap = 32;  // max faces per vertex (lambda ~ 6; P(overflow) ~ 1e-15)

__device__ __forceinline__ void cross3(float ax, float ay, float az,
                                       float bx, float by, float bz,
                                       float& cx, float& cy, float& cz) {
  cx = ay * bz - az * by;
  cy = az * bx - ax * bz;
  cz = ax * by - ay * bx;
}

// Build per-vertex adjacency lists (fixed capacity). ~30K int atomics.
__global__ void build_adj_kernel(const int* __restrict__ faces,
                                 int* __restrict__ cnt,
                                 int* __restrict__ adj) {
  int f = blockIdx.x * blockDim.x + threadIdx.x;
  if (f >= kF) return;
#pragma unroll
  for (int c = 0; c < 3; ++c) {
    int v = faces[f * 3 + c];
    int slot = atomicAdd(&cnt[v], 1);
    if (slot < kCap) adj[v * kCap + slot] = f;
  }
}

// One thread per (batch, face): one cross product per mesh, dense stores.
// fn layout per (b,f): float4 {nx,ny,nz,tx}, float4 {ty,tz,0,0}
__global__ void facenorm_kernel(const float* __restrict__ verts,
                                const float* __restrict__ tverts,
                                const int* __restrict__ faces,
                                float4* __restrict__ fn) {
  int idx = blockIdx.x * blockDim.x + threadIdx.x;
  if (idx >= kB * kF) return;
  int b = idx / kF;
  int f = idx - b * kF;
  int i0 = faces[f * 3 + 0];
  int i1 = faces[f * 3 + 1];
  int i2 = faces[f * 3 + 2];

  float nx, ny, nz, tx, ty, tz;
  {
    const float* vb = verts + (size_t)b * kV * 3;
    float v0x = vb[i0 * 3 + 0], v0y = vb[i0 * 3 + 1], v0z = vb[i0 * 3 + 2];
    float v1x = vb[i1 * 3 + 0], v1y = vb[i1 * 3 + 1], v1z = vb[i1 * 3 + 2];
    float v2x = vb[i2 * 3 + 0], v2y = vb[i2 * 3 + 1], v2z = vb[i2 * 3 + 2];
    cross3(v1x - v0x, v1y - v0y, v1z - v0z, v2x - v0x, v2y - v0y, v2z - v0z,
           nx, ny, nz);
  }
  {
    const float* vb = tverts + (size_t)b * kV * 3;
    // fp-faithful to reference: add 10 to z BEFORE differencing
    float v0x = vb[i0 * 3 + 0], v0y = vb[i0 * 3 + 1], v0z = vb[i0 * 3 + 2] + 10.0f;
    float v1x = vb[i1 * 3 + 0], v1y = vb[i1 * 3 + 1], v1z = vb[i1 * 3 + 2] + 10.0f;
    float v2x = vb[i2 * 3 + 0], v2y = vb[i2 * 3 + 1], v2z = vb[i2 * 3 + 2] + 10.0f;
    cross3(v1x - v0x, v1y - v0y, v1z - v0z, v2x - v0x, v2y - v0y, v2z - v0z,
           tx, ty, tz);
  }
  fn[(size_t)idx * 2 + 0] = make_float4(nx, ny, nz, tx);
  fn[(size_t)idx * 2 + 1] = make_float4(ty, tz, 0.0f, 0.0f);
}

// One thread per (batch, vertex): gather-sum adjacent face normals, normalize.
__global__ void gather_normalize_kernel(const int* __restrict__ cnt,
                                        const int* __restrict__ adj,
                                        const float4* __restrict__ fn,
                                        float* __restrict__ normals,
                                        float* __restrict__ tz,
                                        const float* __restrict__ lights,
                                        float* __restrict__ ldir) {
  int idx = blockIdx.x * blockDim.x + threadIdx.x;
  if (idx < kB * kV) {
    int b = idx / kV;
    int v = idx - b * kV;
    int e = min(cnt[v], kCap);
    float nx = 0.f, ny = 0.f, nz = 0.f, tx = 0.f, ty = 0.f, tzv = 0.f;
    const int* av = adj + v * kCap;
    for (int j = 0; j < e; ++j) {
      int f = av[j];
      size_t k = ((size_t)b * kF + f) * 2;
      float4 a = fn[k];
      float4 c = fn[k + 1];
      nx += a.x;
      ny += a.y;
      nz += a.z;
      tx += a.w;
      ty += c.x;
      tzv += c.y;
    }
    float inv = 1.0f / fmaxf(sqrtf(nx * nx + ny * ny + nz * nz), 1e-6f);
    normals[(size_t)idx * 3 + 0] = nx * inv;
    normals[(size_t)idx * 3 + 1] = ny * inv;
    normals[(size_t)idx * 3 + 2] = nz * inv;
    float invt = 1.0f / fmaxf(sqrtf(tx * tx + ty * ty + tzv * tzv), 1e-6f);
    tz[idx] = tzv * invt;
  }
  if (idx < kB * kL) {
    float dx = lights[idx * 6 + 0];
    float dy = lights[idx * 6 + 1];
    float dz = lights[idx * 6 + 2];
    float inv = 1.0f / fmaxf(sqrtf(dx * dx + dy * dy + dz * dz), 1e-12f);
    ldir[idx * 6 + 0] = dx * inv;
    ldir[idx * 6 + 1] = dy * inv;
    ldir[idx * 6 + 2] = dz * inv;
    ldir[idx * 6 + 3] = lights[idx * 6 + 3];
    ldir[idx * 6 + 4] = lights[idx * 6 + 4];
    ldir[idx * 6 + 5] = lights[idx * 6 + 5];
  }
}

// One thread per pixel.
__global__ void pixel_kernel(const int* __restrict__ p2f,
                             const float* __restrict__ bary,
                             const int* __restrict__ faces,
                             const float* __restrict__ normals,
                             const float* __restrict__ tz,
                             const float* __restrict__ ldir,
                             const float* __restrict__ images,
                             float* __restrict__ out) {
  int pid = blockIdx.x * blockDim.x + threadIdx.x;
  if (pid >= kB * kHW) return;
  int b = pid / kHW;
  int p = pid - b * kHW;

  int f = p2f[pid];
  bool valid = f < kF;
  f = valid ? f : (kF - 1);

  int i0 = faces[f * 3 + 0];
  int i1 = faces[f * 3 + 1];
  int i2 = faces[f * 3 + 2];

  float b0 = bary[(size_t)pid * 3 + 0];
  float b1 = bary[(size_t)pid * 3 + 1];
  float b2 = bary[(size_t)pid * 3 + 2];
  float s = b0 + b1 + b2;
  b0 /= s;
  b1 /= s;
  b2 /= s;

  const float* tzb = tz + (size_t)b * kV;
  float tzi = b0 * tzb[i0] + b1 * tzb[i1] + b2 * tzb[i2];
  bool alpha = valid && (tzi < 0.15f);

  size_t ib = (size_t)b * 3 * kHW + p;
  float o0, o1, o2;
  if (alpha) {
    const float* nb = normals + (size_t)b * kV * 3;
    float nx = b0 * nb[i0 * 3 + 0] + b1 * nb[i1 * 3 + 0] + b2 * nb[i2 * 3 + 0];
    float ny = b0 * nb[i0 * 3 + 1] + b1 * nb[i1 * 3 + 1] + b2 * nb[i2 * 3 + 1];
    float nz = b0 * nb[i0 * 3 + 2] + b1 * nb[i1 * 3 + 2] + b2 * nb[i2 * 3 + 2];
    const float* lb = ldir + (size_t)b * kL * 6;
    float s0 = 0.f, s1 = 0.f, s2 = 0.f;
#pragma unroll
    for (int l = 0; l < kL; ++l) {
      float d = nx * lb[l * 6 + 0] + ny * lb[l * 6 + 1] + nz * lb[l * 6 + 2];
      d = fminf(fmaxf(d, 0.0f), 1.0f);
      s0 += d * lb[l * 6 + 3];
      s1 += d * lb[l * 6 + 4];
      s2 += d * lb[l * 6 + 5];
    }
    const float k = (180.0f / 255.0f) / (float)kL;
    o0 = k * s0;
    o1 = k * s1;
    o2 = k * s2;
  } else {
    o0 = images[ib + 0 * (size_t)kHW];
    o1 = images[ib + 1 * (size_t)kHW];
    o2 = images[ib + 2 * (size_t)kHW];
  }
  out[ib + 0 * (size_t)kHW] = o0;
  out[ib + 1 * (size_t)kHW] = o1;
  out[ib + 2 * (size_t)kHW] = o2;
}

}  // namespace

extern "C" void kernel_launch(void* const* d_in, const int* in_sizes, int n_in,
                              void* d_out, int out_size, void* d_ws, size_t ws_size,
                              hipStream_t stream) {
  const float* vertices = (const float*)d_in[0];
  const float* tvertices = (const float*)d_in[1];
  const float* lights = (const float*)d_in[2];
  const float* images = (const float*)d_in[3];
  const float* bary = (const float*)d_in[4];
  const int* faces = (const int*)d_in[5];
  const int* p2f = (const int*)d_in[6];
  float* out = (float*)d_out;

  // workspace layout (16B-aligned chunks)
  char* ws = (char*)d_ws;
  int* cnt = (int*)ws;                                   // kV ints
  ws += ((size_t)kV * sizeof(int) + 15) & ~15ull;
  int* adj = (int*)ws;                                   // kV*kCap ints
  ws += ((size_t)kV * kCap * sizeof(int) + 15) & ~15ull;
  float4* fn = (float4*)ws;                              // kB*kF*2 float4
  ws += (size_t)kB * kF * 2 * sizeof(float4);
  float* normals = (float*)ws;                           // kB*kV*3
  ws += ((size_t)kB * kV * 3 * sizeof(float) + 15) & ~15ull;
  float* tz = (float*)ws;                                // kB*kV
  ws += ((size_t)kB * kV * sizeof(float) + 15) & ~15ull;
  float* ldir = (float*)ws;                              // kB*kL*6

  hipMemsetAsync(cnt, 0, (size_t)kV * sizeof(int), stream);

  {
    int n = kF;
    build_adj_kernel<<<(n + 255) / 256, 256, 0, stream>>>(faces, cnt, adj);
  }
  {
    int n = kB * kF;
    facenorm_kernel<<<(n + 255) / 256, 256, 0, stream>>>(vertices, tvertices, faces, fn);
  }
  {
    int n = kB * kV;
    gather_normalize_kernel<<<(n + 255) / 256, 256, 0, stream>>>(cnt, adj, fn, normals,
                                                                 tz, lights, ldir);
  }
  {
    int n = kB * kHW;
    pixel_kernel<<<(n + 255) / 256, 256, 0, stream>>>(p2f, bary, faces, normals, tz,
                                                      ldir, images, out);
  }
}

// Round 3
// 59.448 us; speedup vs baseline: 2.1695x; 1.2410x over previous
//
#include <hip/hip_runtime.h>

namespace {

constexpr int kB = 8;
constexpr int kV = 5023;
constexpr int kF = 9976;
constexpr int kH = 512;
constexpr int kW = 512;
constexpr int kL = 5;
constexpr int kHW = kH * kW;
constexpr int kQ = kHW / 4;  // pixel quads per batch
constexpr int kCap = 32;     // max faces per vertex (lambda ~ 6)

__device__ __forceinline__ void cross3(float ax, float ay, float az,
                                       float bx, float by, float bz,
                                       float& cx, float& cy, float& cz) {
  cx = ay * bz - az * by;
  cy = az * bx - ax * bz;
  cz = ax * by - ay * bx;
}

// Fused: threads [0,kF) build vertex->face adjacency (int atomics);
// threads [kF, kF+kB*kF) compute per-(b,f) face normals for both meshes.
__global__ void prep_kernel(const float* __restrict__ verts,
                            const float* __restrict__ tverts,
                            const int* __restrict__ faces,
                            int* __restrict__ cnt,
                            int* __restrict__ adj,
                            float4* __restrict__ fn) {
  int idx = blockIdx.x * blockDim.x + threadIdx.x;
  if (idx < kF) {
    int f = idx;
#pragma unroll
    for (int c = 0; c < 3; ++c) {
      int v = faces[f * 3 + c];
      int slot = atomicAdd(&cnt[v], 1);
      if (slot < kCap) adj[v * kCap + slot] = f;
    }
    return;
  }
  idx -= kF;
  if (idx >= kB * kF) return;
  int b = idx / kF;
  int f = idx - b * kF;
  int i0 = faces[f * 3 + 0];
  int i1 = faces[f * 3 + 1];
  int i2 = faces[f * 3 + 2];

  float nx, ny, nz, tx, ty, tz;
  {
    const float* vb = verts + (size_t)b * kV * 3;
    float v0x = vb[i0 * 3 + 0], v0y = vb[i0 * 3 + 1], v0z = vb[i0 * 3 + 2];
    float v1x = vb[i1 * 3 + 0], v1y = vb[i1 * 3 + 1], v1z = vb[i1 * 3 + 2];
    float v2x = vb[i2 * 3 + 0], v2y = vb[i2 * 3 + 1], v2z = vb[i2 * 3 + 2];
    cross3(v1x - v0x, v1y - v0y, v1z - v0z, v2x - v0x, v2y - v0y, v2z - v0z,
           nx, ny, nz);
  }
  {
    const float* vb = tverts + (size_t)b * kV * 3;
    // fp-faithful to reference: add 10 to z BEFORE differencing
    float v0x = vb[i0 * 3 + 0], v0y = vb[i0 * 3 + 1], v0z = vb[i0 * 3 + 2] + 10.0f;
    float v1x = vb[i1 * 3 + 0], v1y = vb[i1 * 3 + 1], v1z = vb[i1 * 3 + 2] + 10.0f;
    float v2x = vb[i2 * 3 + 0], v2y = vb[i2 * 3 + 1], v2z = vb[i2 * 3 + 2] + 10.0f;
    cross3(v1x - v0x, v1y - v0y, v1z - v0z, v2x - v0x, v2y - v0y, v2z - v0z,
           tx, ty, tz);
  }
  fn[(size_t)idx * 2 + 0] = make_float4(nx, ny, nz, tx);
  fn[(size_t)idx * 2 + 1] = make_float4(ty, tz, 0.0f, 0.0f);
}

// Per (b,v): gather-sum adjacent face normals, normalize. Also light dirs.
__global__ void gather_normalize_kernel(const int* __restrict__ cnt,
                                        const int* __restrict__ adj,
                                        const float4* __restrict__ fn,
                                        float* __restrict__ normals,
                                        float* __restrict__ tz,
                                        const float* __restrict__ lights,
                                        float* __restrict__ ldir) {
  int idx = blockIdx.x * blockDim.x + threadIdx.x;
  if (idx < kB * kV) {
    int b = idx / kV;
    int v = idx - b * kV;
    int e = min(cnt[v], kCap);
    float nx = 0.f, ny = 0.f, nz = 0.f, tx = 0.f, ty = 0.f, tzv = 0.f;
    const int* av = adj + v * kCap;
    for (int j = 0; j < e; ++j) {
      int f = av[j];
      size_t k = ((size_t)b * kF + f) * 2;
      float4 a = fn[k];
      float4 c = fn[k + 1];
      nx += a.x;
      ny += a.y;
      nz += a.z;
      tx += a.w;
      ty += c.x;
      tzv += c.y;
    }
    float inv = 1.0f / fmaxf(sqrtf(nx * nx + ny * ny + nz * nz), 1e-6f);
    normals[(size_t)idx * 3 + 0] = nx * inv;
    normals[(size_t)idx * 3 + 1] = ny * inv;
    normals[(size_t)idx * 3 + 2] = nz * inv;
    float invt = 1.0f / fmaxf(sqrtf(tx * tx + ty * ty + tzv * tzv), 1e-6f);
    tz[idx] = tzv * invt;
  }
  if (idx < kB * kL) {
    float dx = lights[idx * 6 + 0];
    float dy = lights[idx * 6 + 1];
    float dz = lights[idx * 6 + 2];
    float inv = 1.0f / fmaxf(sqrtf(dx * dx + dy * dy + dz * dz), 1e-12f);
    ldir[idx * 6 + 0] = dx * inv;
    ldir[idx * 6 + 1] = dy * inv;
    ldir[idx * 6 + 2] = dz * inv;
    ldir[idx * 6 + 3] = lights[idx * 6 + 3];
    ldir[idx * 6 + 4] = lights[idx * 6 + 4];
    ldir[idx * 6 + 5] = lights[idx * 6 + 5];
  }
}

// Per (b,f): pack the 3 corners' {normal, tz} into 3 float4 — the pixel pass
// then needs only ONE level of indirection after p2f.
__global__ void faceattr_kernel(const int* __restrict__ faces,
                                const float* __restrict__ normals,
                                const float* __restrict__ tz,
                                float4* __restrict__ fattr) {
  int idx = blockIdx.x * blockDim.x + threadIdx.x;
  if (idx >= kB * kF) return;
  int b = idx / kF;
  int f = idx - b * kF;
  int i0 = faces[f * 3 + 0];
  int i1 = faces[f * 3 + 1];
  int i2 = faces[f * 3 + 2];
  const float* nb = normals + (size_t)b * kV * 3;
  const float* tzb = tz + (size_t)b * kV;
  fattr[(size_t)idx * 3 + 0] =
      make_float4(nb[i0 * 3 + 0], nb[i0 * 3 + 1], nb[i0 * 3 + 2], tzb[i0]);
  fattr[(size_t)idx * 3 + 1] =
      make_float4(nb[i1 * 3 + 0], nb[i1 * 3 + 1], nb[i1 * 3 + 2], tzb[i1]);
  fattr[(size_t)idx * 3 + 2] =
      make_float4(nb[i2 * 3 + 0], nb[i2 * 3 + 1], nb[i2 * 3 + 2], tzb[i2]);
}

// 4 pixels per thread: vector loads/stores, 12 independent float4 gathers.
__global__ void __launch_bounds__(256) pixel4_kernel(
    const int4* __restrict__ p2f4,
    const float4* __restrict__ bary4,
    const float4* __restrict__ fattr,
    const float* __restrict__ ldir,
    const float4* __restrict__ img4,
    float4* __restrict__ out4) {
  int g = blockIdx.x * blockDim.x + threadIdx.x;
  if (g >= kB * kQ) return;
  int b = g / kQ;
  int q = g - b * kQ;

  int4 f4 = p2f4[g];
  float4 w0 = bary4[(size_t)g * 3 + 0];
  float4 w1 = bary4[(size_t)g * 3 + 1];
  float4 w2 = bary4[(size_t)g * 3 + 2];

  int fi[4] = {f4.x, f4.y, f4.z, f4.w};
  float bw[4][3] = {{w0.x, w0.y, w0.z},
                    {w0.w, w1.x, w1.y},
                    {w1.z, w1.w, w2.x},
                    {w2.y, w2.z, w2.w}};

  // Issue all 12 gathers (independent -> deep MLP).
  float4 a[4][3];
  bool valid[4];
#pragma unroll
  for (int k = 0; k < 4; ++k) {
    bool v = fi[k] < kF;
    valid[k] = v;
    int f = v ? fi[k] : (kF - 1);
    size_t base = ((size_t)b * kF + f) * 3;
    a[k][0] = fattr[base + 0];
    a[k][1] = fattr[base + 1];
    a[k][2] = fattr[base + 2];
  }

  size_t ibase = (size_t)b * 3 * kQ + q;
  float4 im0 = img4[ibase + 0 * (size_t)kQ];
  float4 im1 = img4[ibase + 1 * (size_t)kQ];
  float4 im2 = img4[ibase + 2 * (size_t)kQ];
  float im[3][4] = {{im0.x, im0.y, im0.z, im0.w},
                    {im1.x, im1.y, im1.z, im1.w},
                    {im2.x, im2.y, im2.z, im2.w}};

  const float* lb = ldir + (size_t)b * kL * 6;
  float lv[kL][6];
#pragma unroll
  for (int l = 0; l < kL; ++l)
#pragma unroll
    for (int c = 0; c < 6; ++c) lv[l][c] = lb[l * 6 + c];

  float o[3][4];
#pragma unroll
  for (int k = 0; k < 4; ++k) {
    float b0 = bw[k][0], b1 = bw[k][1], b2 = bw[k][2];
    float inv = 1.0f / (b0 + b1 + b2);
    b0 *= inv;
    b1 *= inv;
    b2 *= inv;
    float4 A = a[k][0], Bv = a[k][1], C = a[k][2];
    float tzi = b0 * A.w + b1 * Bv.w + b2 * C.w;
    bool alpha = valid[k] && (tzi < 0.15f);
    float nx = b0 * A.x + b1 * Bv.x + b2 * C.x;
    float ny = b0 * A.y + b1 * Bv.y + b2 * C.y;
    float nz = b0 * A.z + b1 * Bv.z + b2 * C.z;
    float s0 = 0.f, s1 = 0.f, s2 = 0.f;
#pragma unroll
    for (int l = 0; l < kL; ++l) {
      float d = nx * lv[l][0] + ny * lv[l][1] + nz * lv[l][2];
      d = fminf(fmaxf(d, 0.0f), 1.0f);
      s0 += d * lv[l][3];
      s1 += d * lv[l][4];
      s2 += d * lv[l][5];
    }
    const float kk = (180.0f / 255.0f) / (float)kL;
    o[0][k] = alpha ? kk * s0 : im[0][k];
    o[1][k] = alpha ? kk * s1 : im[1][k];
    o[2][k] = alpha ? kk * s2 : im[2][k];
  }

  out4[ibase + 0 * (size_t)kQ] = make_float4(o[0][0], o[0][1], o[0][2], o[0][3]);
  out4[ibase + 1 * (size_t)kQ] = make_float4(o[1][0], o[1][1], o[1][2], o[1][3]);
  out4[ibase + 2 * (size_t)kQ] = make_float4(o[2][0], o[2][1], o[2][2], o[2][3]);
}

}  // namespace

extern "C" void kernel_launch(void* const* d_in, const int* in_sizes, int n_in,
                              void* d_out, int out_size, void* d_ws, size_t ws_size,
                              hipStream_t stream) {
  const float* vertices = (const float*)d_in[0];
  const float* tvertices = (const float*)d_in[1];
  const float* lights = (const float*)d_in[2];
  const float* images = (const float*)d_in[3];
  const float* bary = (const float*)d_in[4];
  const int* faces = (const int*)d_in[5];
  const int* p2f = (const int*)d_in[6];
  float* out = (float*)d_out;

  // workspace layout (16B-aligned chunks)
  char* ws = (char*)d_ws;
  int* cnt = (int*)ws;                                   // kV ints
  ws += ((size_t)kV * sizeof(int) + 15) & ~15ull;
  int* adj = (int*)ws;                                   // kV*kCap ints
  ws += ((size_t)kV * kCap * sizeof(int) + 15) & ~15ull;
  float4* fn = (float4*)ws;                              // kB*kF*2 float4
  ws += (size_t)kB * kF * 2 * sizeof(float4);
  float* normals = (float*)ws;                           // kB*kV*3
  ws += ((size_t)kB * kV * 3 * sizeof(float) + 15) & ~15ull;
  float* tz = (float*)ws;                                // kB*kV
  ws += ((size_t)kB * kV * sizeof(float) + 15) & ~15ull;
  float* ldir = (float*)ws;                              // kB*kL*6
  ws += ((size_t)kB * kL * 6 * sizeof(float) + 15) & ~15ull;
  float4* fattr = (float4*)ws;                           // kB*kF*3 float4

  hipMemsetAsync(cnt, 0, (size_t)kV * sizeof(int), stream);

  {
    int n = kF + kB * kF;
    prep_kernel<<<(n + 255) / 256, 256, 0, stream>>>(vertices, tvertices, faces, cnt,
                                                     adj, fn);
  }
  {
    int n = kB * kV;
    gather_normalize_kernel<<<(n + 255) / 256, 256, 0, stream>>>(cnt, adj, fn, normals,
                                                                 tz, lights, ldir);
  }
  {
    int n = kB * kF;
    faceattr_kernel<<<(n + 255) / 256, 256, 0, stream>>>(faces, normals, tz, fattr);
  }
  {
    int n = kB * kQ;
    pixel4_kernel<<<(n + 255) / 256, 256, 0, stream>>>((const int4*)p2f, (const float4*)bary,
                                                       fattr, ldir, (const float4*)images,
                                                       (float4*)out);
  }
}

// Round 4
// 57.170 us; speedup vs baseline: 2.2559x; 1.0398x over previous
//
#include <hip/hip_runtime.h>

namespace {

constexpr int kB = 8;
constexpr int kV = 5023;
constexpr int kF = 9976;
constexpr int kH = 512;
constexpr int kW = 512;
constexpr int kL = 5;
constexpr int kHW = kH * kW;
constexpr int kQ = kHW / 4;  // pixel quads per batch
constexpr int kCap = 32;     // max faces per vertex (lambda ~ 6)

__device__ __forceinline__ void cross3(float ax, float ay, float az,
                                       float bx, float by, float bz,
                                       float& cx, float& cy, float& cz) {
  cx = ay * bz - az * by;
  cy = az * bx - ax * bz;
  cz = ax * by - ay * bx;
}

// Zero the adjacency counters (replaces the 39us rocclr fill) and
// pre-normalize light directions.
__global__ void init_kernel(int* __restrict__ cnt,
                            const float* __restrict__ lights,
                            float* __restrict__ ldir) {
  int idx = blockIdx.x * blockDim.x + threadIdx.x;
  for (int i = idx; i < kV; i += gridDim.x * blockDim.x) cnt[i] = 0;
  if (idx < kB * kL) {
    float dx = lights[idx * 6 + 0];
    float dy = lights[idx * 6 + 1];
    float dz = lights[idx * 6 + 2];
    float inv = 1.0f / fmaxf(sqrtf(dx * dx + dy * dy + dz * dz), 1e-12f);
    ldir[idx * 6 + 0] = dx * inv;
    ldir[idx * 6 + 1] = dy * inv;
    ldir[idx * 6 + 2] = dz * inv;
    ldir[idx * 6 + 3] = lights[idx * 6 + 3];
    ldir[idx * 6 + 4] = lights[idx * 6 + 4];
    ldir[idx * 6 + 5] = lights[idx * 6 + 5];
  }
}

// Fused: threads [0,kF) build vertex->face adjacency (int atomics);
// threads [kF, kF+kB*kF) compute per-(b,f) face normals for both meshes.
__global__ void prep_kernel(const float* __restrict__ verts,
                            const float* __restrict__ tverts,
                            const int* __restrict__ faces,
                            int* __restrict__ cnt,
                            int* __restrict__ adj,
                            float4* __restrict__ fn) {
  int idx = blockIdx.x * blockDim.x + threadIdx.x;
  if (idx < kF) {
    int f = idx;
#pragma unroll
    for (int c = 0; c < 3; ++c) {
      int v = faces[f * 3 + c];
      int slot = atomicAdd(&cnt[v], 1);
      if (slot < kCap) adj[v * kCap + slot] = f;
    }
    return;
  }
  idx -= kF;
  if (idx >= kB * kF) return;
  int b = idx / kF;
  int f = idx - b * kF;
  int i0 = faces[f * 3 + 0];
  int i1 = faces[f * 3 + 1];
  int i2 = faces[f * 3 + 2];

  float nx, ny, nz, tx, ty, tz;
  {
    const float* vb = verts + (size_t)b * kV * 3;
    float v0x = vb[i0 * 3 + 0], v0y = vb[i0 * 3 + 1], v0z = vb[i0 * 3 + 2];
    float v1x = vb[i1 * 3 + 0], v1y = vb[i1 * 3 + 1], v1z = vb[i1 * 3 + 2];
    float v2x = vb[i2 * 3 + 0], v2y = vb[i2 * 3 + 1], v2z = vb[i2 * 3 + 2];
    cross3(v1x - v0x, v1y - v0y, v1z - v0z, v2x - v0x, v2y - v0y, v2z - v0z,
           nx, ny, nz);
  }
  {
    const float* vb = tverts + (size_t)b * kV * 3;
    // fp-faithful to reference: add 10 to z BEFORE differencing
    float v0x = vb[i0 * 3 + 0], v0y = vb[i0 * 3 + 1], v0z = vb[i0 * 3 + 2] + 10.0f;
    float v1x = vb[i1 * 3 + 0], v1y = vb[i1 * 3 + 1], v1z = vb[i1 * 3 + 2] + 10.0f;
    float v2x = vb[i2 * 3 + 0], v2y = vb[i2 * 3 + 1], v2z = vb[i2 * 3 + 2] + 10.0f;
    cross3(v1x - v0x, v1y - v0y, v1z - v0z, v2x - v0x, v2y - v0y, v2z - v0z,
           tx, ty, tz);
  }
  fn[(size_t)idx * 2 + 0] = make_float4(nx, ny, nz, tx);
  fn[(size_t)idx * 2 + 1] = make_float4(ty, tz, 0.0f, 0.0f);
}

// Per (b,v): gather-sum adjacent face normals, normalize.
__global__ void gather_normalize_kernel(const int* __restrict__ cnt,
                                        const int* __restrict__ adj,
                                        const float4* __restrict__ fn,
                                        float* __restrict__ normals,
                                        float* __restrict__ tz) {
  int idx = blockIdx.x * blockDim.x + threadIdx.x;
  if (idx >= kB * kV) return;
  int b = idx / kV;
  int v = idx - b * kV;
  int e = min(cnt[v], kCap);
  float nx = 0.f, ny = 0.f, nz = 0.f, tx = 0.f, ty = 0.f, tzv = 0.f;
  const int* av = adj + v * kCap;
  for (int j = 0; j < e; ++j) {
    int f = av[j];
    size_t k = ((size_t)b * kF + f) * 2;
    float4 a = fn[k];
    float4 c = fn[k + 1];
    nx += a.x;
    ny += a.y;
    nz += a.z;
    tx += a.w;
    ty += c.x;
    tzv += c.y;
  }
  float inv = 1.0f / fmaxf(sqrtf(nx * nx + ny * ny + nz * nz), 1e-6f);
  normals[(size_t)idx * 3 + 0] = nx * inv;
  normals[(size_t)idx * 3 + 1] = ny * inv;
  normals[(size_t)idx * 3 + 2] = nz * inv;
  float invt = 1.0f / fmaxf(sqrtf(tx * tx + ty * ty + tzv * tzv), 1e-6f);
  tz[idx] = tzv * invt;
}

// Per (b,f): pack the 3 corners' {normal, tz} into 3 float4 — the pixel pass
// then needs only ONE level of indirection after p2f.
__global__ void faceattr_kernel(const int* __restrict__ faces,
                                const float* __restrict__ normals,
                                const float* __restrict__ tz,
                                float4* __restrict__ fattr) {
  int idx = blockIdx.x * blockDim.x + threadIdx.x;
  if (idx >= kB * kF) return;
  int b = idx / kF;
  int f = idx - b * kF;
  int i0 = faces[f * 3 + 0];
  int i1 = faces[f * 3 + 1];
  int i2 = faces[f * 3 + 2];
  const float* nb = normals + (size_t)b * kV * 3;
  const float* tzb = tz + (size_t)b * kV;
  fattr[(size_t)idx * 3 + 0] =
      make_float4(nb[i0 * 3 + 0], nb[i0 * 3 + 1], nb[i0 * 3 + 2], tzb[i0]);
  fattr[(size_t)idx * 3 + 1] =
      make_float4(nb[i1 * 3 + 0], nb[i1 * 3 + 1], nb[i1 * 3 + 2], tzb[i1]);
  fattr[(size_t)idx * 3 + 2] =
      make_float4(nb[i2 * 3 + 0], nb[i2 * 3 + 1], nb[i2 * 3 + 2], tzb[i2]);
}

// 4 pixels per thread: vector loads/stores, 12 independent float4 gathers.
__global__ void __launch_bounds__(256) pixel4_kernel(
    const int4* __restrict__ p2f4,
    const float4* __restrict__ bary4,
    const float4* __restrict__ fattr,
    const float* __restrict__ ldir,
    const float4* __restrict__ img4,
    float4* __restrict__ out4) {
  int g = blockIdx.x * blockDim.x + threadIdx.x;
  if (g >= kB * kQ) return;
  int b = g / kQ;
  int q = g - b * kQ;

  int4 f4 = p2f4[g];
  float4 w0 = bary4[(size_t)g * 3 + 0];
  float4 w1 = bary4[(size_t)g * 3 + 1];
  float4 w2 = bary4[(size_t)g * 3 + 2];

  int fi[4] = {f4.x, f4.y, f4.z, f4.w};
  float bw[4][3] = {{w0.x, w0.y, w0.z},
                    {w0.w, w1.x, w1.y},
                    {w1.z, w1.w, w2.x},
                    {w2.y, w2.z, w2.w}};

  // Issue all 12 gathers (independent -> deep MLP).
  float4 a[4][3];
  bool valid[4];
#pragma unroll
  for (int k = 0; k < 4; ++k) {
    bool v = fi[k] < kF;
    valid[k] = v;
    int f = v ? fi[k] : (kF - 1);
    size_t base = ((size_t)b * kF + f) * 3;
    a[k][0] = fattr[base + 0];
    a[k][1] = fattr[base + 1];
    a[k][2] = fattr[base + 2];
  }

  size_t ibase = (size_t)b * 3 * kQ + q;
  float4 im0 = img4[ibase + 0 * (size_t)kQ];
  float4 im1 = img4[ibase + 1 * (size_t)kQ];
  float4 im2 = img4[ibase + 2 * (size_t)kQ];
  float im[3][4] = {{im0.x, im0.y, im0.z, im0.w},
                    {im1.x, im1.y, im1.z, im1.w},
                    {im2.x, im2.y, im2.z, im2.w}};

  const float* lb = ldir + (size_t)b * kL * 6;
  float lv[kL][6];
#pragma unroll
  for (int l = 0; l < kL; ++l)
#pragma unroll
    for (int c = 0; c < 6; ++c) lv[l][c] = lb[l * 6 + c];

  float o[3][4];
#pragma unroll
  for (int k = 0; k < 4; ++k) {
    float b0 = bw[k][0], b1 = bw[k][1], b2 = bw[k][2];
    float inv = 1.0f / (b0 + b1 + b2);
    b0 *= inv;
    b1 *= inv;
    b2 *= inv;
    float4 A = a[k][0], Bv = a[k][1], C = a[k][2];
    float tzi = b0 * A.w + b1 * Bv.w + b2 * C.w;
    bool alpha = valid[k] && (tzi < 0.15f);
    float nx = b0 * A.x + b1 * Bv.x + b2 * C.x;
    float ny = b0 * A.y + b1 * Bv.y + b2 * C.y;
    float nz = b0 * A.z + b1 * Bv.z + b2 * C.z;
    float s0 = 0.f, s1 = 0.f, s2 = 0.f;
#pragma unroll
    for (int l = 0; l < kL; ++l) {
      float d = nx * lv[l][0] + ny * lv[l][1] + nz * lv[l][2];
      d = fminf(fmaxf(d, 0.0f), 1.0f);
      s0 += d * lv[l][3];
      s1 += d * lv[l][4];
      s2 += d * lv[l][5];
    }
    const float kk = (180.0f / 255.0f) / (float)kL;
    o[0][k] = alpha ? kk * s0 : im[0][k];
    o[1][k] = alpha ? kk * s1 : im[1][k];
    o[2][k] = alpha ? kk * s2 : im[2][k];
  }

  out4[ibase + 0 * (size_t)kQ] = make_float4(o[0][0], o[0][1], o[0][2], o[0][3]);
  out4[ibase + 1 * (size_t)kQ] = make_float4(o[1][0], o[1][1], o[1][2], o[1][3]);
  out4[ibase + 2 * (size_t)kQ] = make_float4(o[2][0], o[2][1], o[2][2], o[2][3]);
}

}  // namespace

extern "C" void kernel_launch(void* const* d_in, const int* in_sizes, int n_in,
                              void* d_out, int out_size, void* d_ws, size_t ws_size,
                              hipStream_t stream) {
  const float* vertices = (const float*)d_in[0];
  const float* tvertices = (const float*)d_in[1];
  const float* lights = (const float*)d_in[2];
  const float* images = (const float*)d_in[3];
  const float* bary = (const float*)d_in[4];
  const int* faces = (const int*)d_in[5];
  const int* p2f = (const int*)d_in[6];
  float* out = (float*)d_out;

  // workspace layout (16B-aligned chunks)
  char* ws = (char*)d_ws;
  int* cnt = (int*)ws;                                   // kV ints
  ws += ((size_t)kV * sizeof(int) + 15) & ~15ull;
  int* adj = (int*)ws;                                   // kV*kCap ints
  ws += ((size_t)kV * kCap * sizeof(int) + 15) & ~15ull;
  float4* fn = (float4*)ws;                              // kB*kF*2 float4
  ws += (size_t)kB * kF * 2 * sizeof(float4);
  float* normals = (float*)ws;                           // kB*kV*3
  ws += ((size_t)kB * kV * 3 * sizeof(float) + 15) & ~15ull;
  float* tz = (float*)ws;                                // kB*kV
  ws += ((size_t)kB * kV * sizeof(float) + 15) & ~15ull;
  float* ldir = (float*)ws;                              // kB*kL*6
  ws += ((size_t)kB * kL * 6 * sizeof(float) + 15) & ~15ull;
  float4* fattr = (float4*)ws;                           // kB*kF*3 float4

  {
    // zero cnt + normalize lights (replaces hipMemsetAsync's slow fill)
    init_kernel<<<20, 256, 0, stream>>>(cnt, lights, ldir);
  }
  {
    int n = kF + kB * kF;
    prep_kernel<<<(n + 255) / 256, 256, 0, stream>>>(vertices, tvertices, faces, cnt,
                                                     adj, fn);
  }
  {
    int n = kB * kV;
    gather_normalize_kernel<<<(n + 255) / 256, 256, 0, stream>>>(cnt, adj, fn, normals,
                                                                 tz);
  }
  {
    int n = kB * kF;
    faceattr_kernel<<<(n + 255) / 256, 256, 0, stream>>>(faces, normals, tz, fattr);
  }
  {
    int n = kB * kQ;
    pixel4_kernel<<<(n + 255) / 256, 256, 0, stream>>>((const int4*)p2f, (const float4*)bary,
                                                       fattr, ldir, (const float4*)images,
                                                       (float4*)out);
  }
}

// Round 5
// 50.641 us; speedup vs baseline: 2.5468x; 1.1289x over previous
//
#include <hip/hip_runtime.h>
#include <stdint.h>

namespace {

constexpr int kB = 8;
constexpr int kV = 5023;
constexpr int kF = 9976;
constexpr int kH = 512;
constexpr int kW = 512;
constexpr int kL = 5;
constexpr int kHW = kH * kW;
constexpr int kQ = kHW / 4;  // pixel quads per batch
constexpr int kCap = 32;     // max faces per vertex (lambda ~ 6)

typedef float nfloat4 __attribute__((ext_vector_type(4)));

__device__ __forceinline__ float h2f(uint32_t u) {
  _Float16 h;
  uint16_t s = (uint16_t)u;
  __builtin_memcpy(&h, &s, 2);
  return (float)h;
}
__device__ __forceinline__ uint32_t f2h(float f) {
  _Float16 h = (_Float16)f;
  uint16_t s;
  __builtin_memcpy(&s, &h, 2);
  return (uint32_t)s;
}

__device__ __forceinline__ void cross3(float ax, float ay, float az,
                                       float bx, float by, float bz,
                                       float& cx, float& cy, float& cz) {
  cx = ay * bz - az * by;
  cy = az * bx - ax * bz;
  cz = ax * by - ay * bx;
}

// Zero adjacency counters + pre-normalize lights into packed float4 pairs.
__global__ void init_kernel(int* __restrict__ cnt,
                            const float* __restrict__ lights,
                            float4* __restrict__ ldir4) {
  int idx = blockIdx.x * blockDim.x + threadIdx.x;
  for (int i = idx; i < kV; i += gridDim.x * blockDim.x) cnt[i] = 0;
  if (idx < kB * kL) {
    float dx = lights[idx * 6 + 0];
    float dy = lights[idx * 6 + 1];
    float dz = lights[idx * 6 + 2];
    float inv = 1.0f / fmaxf(sqrtf(dx * dx + dy * dy + dz * dz), 1e-12f);
    ldir4[idx * 2 + 0] = make_float4(dx * inv, dy * inv, dz * inv, 0.0f);
    ldir4[idx * 2 + 1] =
        make_float4(lights[idx * 6 + 3], lights[idx * 6 + 4], lights[idx * 6 + 5], 0.0f);
  }
}

// Fused: threads [0,kF) build vertex->face adjacency (int atomics);
// threads [kF, kF+kB*kF) compute per-(b,f) face normals for both meshes.
__global__ void prep_kernel(const float* __restrict__ verts,
                            const float* __restrict__ tverts,
                            const int* __restrict__ faces,
                            int* __restrict__ cnt,
                            int* __restrict__ adj,
                            float4* __restrict__ fn) {
  int idx = blockIdx.x * blockDim.x + threadIdx.x;
  if (idx < kF) {
    int f = idx;
#pragma unroll
    for (int c = 0; c < 3; ++c) {
      int v = faces[f * 3 + c];
      int slot = atomicAdd(&cnt[v], 1);
      if (slot < kCap) adj[v * kCap + slot] = f;
    }
    return;
  }
  idx -= kF;
  if (idx >= kB * kF) return;
  int b = idx / kF;
  int f = idx - b * kF;
  int i0 = faces[f * 3 + 0];
  int i1 = faces[f * 3 + 1];
  int i2 = faces[f * 3 + 2];

  float nx, ny, nz, tx, ty, tz;
  {
    const float* vb = verts + (size_t)b * kV * 3;
    float v0x = vb[i0 * 3 + 0], v0y = vb[i0 * 3 + 1], v0z = vb[i0 * 3 + 2];
    float v1x = vb[i1 * 3 + 0], v1y = vb[i1 * 3 + 1], v1z = vb[i1 * 3 + 2];
    float v2x = vb[i2 * 3 + 0], v2y = vb[i2 * 3 + 1], v2z = vb[i2 * 3 + 2];
    cross3(v1x - v0x, v1y - v0y, v1z - v0z, v2x - v0x, v2y - v0y, v2z - v0z,
           nx, ny, nz);
  }
  {
    const float* vb = tverts + (size_t)b * kV * 3;
    // fp-faithful to reference: add 10 to z BEFORE differencing
    float v0x = vb[i0 * 3 + 0], v0y = vb[i0 * 3 + 1], v0z = vb[i0 * 3 + 2] + 10.0f;
    float v1x = vb[i1 * 3 + 0], v1y = vb[i1 * 3 + 1], v1z = vb[i1 * 3 + 2] + 10.0f;
    float v2x = vb[i2 * 3 + 0], v2y = vb[i2 * 3 + 1], v2z = vb[i2 * 3 + 2] + 10.0f;
    cross3(v1x - v0x, v1y - v0y, v1z - v0z, v2x - v0x, v2y - v0y, v2z - v0z,
           tx, ty, tz);
  }
  fn[(size_t)idx * 2 + 0] = make_float4(nx, ny, nz, tx);
  fn[(size_t)idx * 2 + 1] = make_float4(ty, tz, 0.0f, 0.0f);
}

// Per (b,v): gather-sum adjacent face normals, normalize.
__global__ void gather_normalize_kernel(const int* __restrict__ cnt,
                                        const int* __restrict__ adj,
                                        const float4* __restrict__ fn,
                                        float* __restrict__ normals,
                                        float* __restrict__ tz) {
  int idx = blockIdx.x * blockDim.x + threadIdx.x;
  if (idx >= kB * kV) return;
  int b = idx / kV;
  int v = idx - b * kV;
  int e = min(cnt[v], kCap);
  float nx = 0.f, ny = 0.f, nz = 0.f, tx = 0.f, ty = 0.f, tzv = 0.f;
  const int* av = adj + v * kCap;
  for (int j = 0; j < e; ++j) {
    int f = av[j];
    size_t k = ((size_t)b * kF + f) * 2;
    float4 a = fn[k];
    float4 c = fn[k + 1];
    nx += a.x;
    ny += a.y;
    nz += a.z;
    tx += a.w;
    ty += c.x;
    tzv += c.y;
  }
  float inv = 1.0f / fmaxf(sqrtf(nx * nx + ny * ny + nz * nz), 1e-6f);
  normals[(size_t)idx * 3 + 0] = nx * inv;
  normals[(size_t)idx * 3 + 1] = ny * inv;
  normals[(size_t)idx * 3 + 2] = nz * inv;
  float invt = 1.0f / fmaxf(sqrtf(tx * tx + ty * ty + tzv * tzv), 1e-6f);
  tz[idx] = tzv * invt;
}

// Per (b,f): pack corners into 32B: uint4{n0xy,n0z|n1x,n1yz,n2xy (fp16)} +
// uint4{n2z fp16, tz0 f32, tz1 f32, tz2 f32}. Normals fp16 (continuous path),
// tz fp32 (feeds the discontinuous <0.15 mask).
__global__ void faceattr_kernel(const int* __restrict__ faces,
                                const float* __restrict__ normals,
                                const float* __restrict__ tz,
                                uint4* __restrict__ fattr) {
  int idx = blockIdx.x * blockDim.x + threadIdx.x;
  if (idx >= kB * kF) return;
  int b = idx / kF;
  int f = idx - b * kF;
  int i0 = faces[f * 3 + 0];
  int i1 = faces[f * 3 + 1];
  int i2 = faces[f * 3 + 2];
  const float* nb = normals + (size_t)b * kV * 3;
  const float* tzb = tz + (size_t)b * kV;
  uint32_t h[9];
  h[0] = f2h(nb[i0 * 3 + 0]);
  h[1] = f2h(nb[i0 * 3 + 1]);
  h[2] = f2h(nb[i0 * 3 + 2]);
  h[3] = f2h(nb[i1 * 3 + 0]);
  h[4] = f2h(nb[i1 * 3 + 1]);
  h[5] = f2h(nb[i1 * 3 + 2]);
  h[6] = f2h(nb[i2 * 3 + 0]);
  h[7] = f2h(nb[i2 * 3 + 1]);
  h[8] = f2h(nb[i2 * 3 + 2]);
  uint4 w0, w1;
  w0.x = h[0] | (h[1] << 16);
  w0.y = h[2] | (h[3] << 16);
  w0.z = h[4] | (h[5] << 16);
  w0.w = h[6] | (h[7] << 16);
  w1.x = h[8];
  w1.y = __float_as_uint(tzb[i0]);
  w1.z = __float_as_uint(tzb[i1]);
  w1.w = __float_as_uint(tzb[i2]);
  fattr[(size_t)idx * 2 + 0] = w0;
  fattr[(size_t)idx * 2 + 1] = w1;
}

// 4 pixels per thread: 8 independent 16B gathers, SMEM light loads,
// non-temporal output stores (keep fattr/bary resident in L2).
__global__ void __launch_bounds__(256) pixel4_kernel(
    const int4* __restrict__ p2f4,
    const float4* __restrict__ bary4,
    const uint4* __restrict__ fattr,
    const float4* __restrict__ ldir4,
    const float4* __restrict__ img4,
    float4* __restrict__ out4) {
  int g = blockIdx.x * blockDim.x + threadIdx.x;
  if (g >= kB * kQ) return;
  int b = g / kQ;
  int q = g - b * kQ;

  int4 f4 = p2f4[g];
  float4 w0 = bary4[(size_t)g * 3 + 0];
  float4 w1 = bary4[(size_t)g * 3 + 1];
  float4 w2 = bary4[(size_t)g * 3 + 2];

  int fi[4] = {f4.x, f4.y, f4.z, f4.w};
  float bw[4][3] = {{w0.x, w0.y, w0.z},
                    {w0.w, w1.x, w1.y},
                    {w1.z, w1.w, w2.x},
                    {w2.y, w2.z, w2.w}};

  // Issue all 8 gathers (independent -> deep MLP).
  uint4 A[4], T[4];
  bool valid[4];
#pragma unroll
  for (int k = 0; k < 4; ++k) {
    bool v = fi[k] < kF;
    valid[k] = v;
    int f = v ? fi[k] : (kF - 1);
    size_t base = ((size_t)b * kF + f) * 2;
    A[k] = fattr[base + 0];
    T[k] = fattr[base + 1];
  }

  size_t ibase = (size_t)b * 3 * kQ + q;
  float4 im0 = img4[ibase + 0 * (size_t)kQ];
  float4 im1 = img4[ibase + 1 * (size_t)kQ];
  float4 im2 = img4[ibase + 2 * (size_t)kQ];
  float im[3][4] = {{im0.x, im0.y, im0.z, im0.w},
                    {im1.x, im1.y, im1.z, im1.w},
                    {im2.x, im2.y, im2.z, im2.w}};

  // Light data: wave-uniform b -> scalar (SMEM) loads.
  int bu = __builtin_amdgcn_readfirstlane(b);
  const float4* lb4 = ldir4 + (size_t)bu * kL * 2;
  float ld[kL][3], lc[kL][3];
#pragma unroll
  for (int l = 0; l < kL; ++l) {
    float4 d = lb4[l * 2 + 0];
    float4 c = lb4[l * 2 + 1];
    ld[l][0] = d.x;
    ld[l][1] = d.y;
    ld[l][2] = d.z;
    lc[l][0] = c.x;
    lc[l][1] = c.y;
    lc[l][2] = c.z;
  }

  float o[3][4];
#pragma unroll
  for (int k = 0; k < 4; ++k) {
    float b0 = bw[k][0], b1 = bw[k][1], b2 = bw[k][2];
    float inv = 1.0f / (b0 + b1 + b2);
    b0 *= inv;
    b1 *= inv;
    b2 *= inv;
    float n0x = h2f(A[k].x), n0y = h2f(A[k].x >> 16);
    float n0z = h2f(A[k].y), n1x = h2f(A[k].y >> 16);
    float n1y = h2f(A[k].z), n1z = h2f(A[k].z >> 16);
    float n2x = h2f(A[k].w), n2y = h2f(A[k].w >> 16);
    float n2z = h2f(T[k].x);
    float tz0 = __uint_as_float(T[k].y);
    float tz1 = __uint_as_float(T[k].z);
    float tz2 = __uint_as_float(T[k].w);

    float tzi = b0 * tz0 + b1 * tz1 + b2 * tz2;
    bool alpha = valid[k] && (tzi < 0.15f);
    float nx = b0 * n0x + b1 * n1x + b2 * n2x;
    float ny = b0 * n0y + b1 * n1y + b2 * n2y;
    float nz = b0 * n0z + b1 * n1z + b2 * n2z;
    float s0 = 0.f, s1 = 0.f, s2 = 0.f;
#pragma unroll
    for (int l = 0; l < kL; ++l) {
      float d = nx * ld[l][0] + ny * ld[l][1] + nz * ld[l][2];
      d = fminf(fmaxf(d, 0.0f), 1.0f);
      s0 += d * lc[l][0];
      s1 += d * lc[l][1];
      s2 += d * lc[l][2];
    }
    const float kk = (180.0f / 255.0f) / (float)kL;
    o[0][k] = alpha ? kk * s0 : im[0][k];
    o[1][k] = alpha ? kk * s1 : im[1][k];
    o[2][k] = alpha ? kk * s2 : im[2][k];
  }

#pragma unroll
  for (int c = 0; c < 3; ++c) {
    nfloat4 v = {o[c][0], o[c][1], o[c][2], o[c][3]};
    __builtin_nontemporal_store(v, (nfloat4*)&out4[ibase + c * (size_t)kQ]);
  }
}

}  // namespace

extern "C" void kernel_launch(void* const* d_in, const int* in_sizes, int n_in,
                              void* d_out, int out_size, void* d_ws, size_t ws_size,
                              hipStream_t stream) {
  const float* vertices = (const float*)d_in[0];
  const float* tvertices = (const float*)d_in[1];
  const float* lights = (const float*)d_in[2];
  const float* images = (const float*)d_in[3];
  const float* bary = (const float*)d_in[4];
  const int* faces = (const int*)d_in[5];
  const int* p2f = (const int*)d_in[6];
  float* out = (float*)d_out;

  // workspace layout (16B-aligned chunks)
  char* ws = (char*)d_ws;
  int* cnt = (int*)ws;                                   // kV ints
  ws += ((size_t)kV * sizeof(int) + 15) & ~15ull;
  int* adj = (int*)ws;                                   // kV*kCap ints
  ws += ((size_t)kV * kCap * sizeof(int) + 15) & ~15ull;
  float4* fn = (float4*)ws;                              // kB*kF*2 float4
  ws += (size_t)kB * kF * 2 * sizeof(float4);
  float* normals = (float*)ws;                           // kB*kV*3
  ws += ((size_t)kB * kV * 3 * sizeof(float) + 15) & ~15ull;
  float* tz = (float*)ws;                                // kB*kV
  ws += ((size_t)kB * kV * sizeof(float) + 15) & ~15ull;
  float4* ldir4 = (float4*)ws;                           // kB*kL*2 float4
  ws += (size_t)kB * kL * 2 * sizeof(float4);
  uint4* fattr = (uint4*)ws;                             // kB*kF*2 uint4

  {
    init_kernel<<<20, 256, 0, stream>>>(cnt, lights, ldir4);
  }
  {
    int n = kF + kB * kF;
    prep_kernel<<<(n + 255) / 256, 256, 0, stream>>>(vertices, tvertices, faces, cnt,
                                                     adj, fn);
  }
  {
    int n = kB * kV;
    gather_normalize_kernel<<<(n + 255) / 256, 256, 0, stream>>>(cnt, adj, fn, normals,
                                                                 tz);
  }
  {
    int n = kB * kF;
    faceattr_kernel<<<(n + 255) / 256, 256, 0, stream>>>(faces, normals, tz, fattr);
  }
  {
    int n = kB * kQ;
    pixel4_kernel<<<(n + 255) / 256, 256, 0, stream>>>((const int4*)p2f, (const float4*)bary,
                                                       fattr, ldir4, (const float4*)images,
                                                       (float4*)out);
  }
}